// Round 2
// baseline (1568.272 us; speedup 1.0000x reference)
//
#include <hip/hip_runtime.h>
#include <stdint.h>

// ============================================================================
// Encoder (6-layer rel-pos transformer), MI355X. f32 in/out, bf16 internals.
// R7: new gemm_bt4 for the N=512 GEMMs (O-proj, FFN2) — 64x64 block tile,
// 4 waves x 32x32/wave => 3072 waves (12/CU) vs 768 (3/CU) before; reg-staged
// double-buffered LDS with ONE barrier per K-step (flash_attn R6 pattern);
// setprio around MFMA. Attacks the 7%-occupancy latency stall that made
// FFN2 42 us (roofline ~6.5 us MFMA / ~5.4 us HBM).
// ============================================================================

typedef unsigned short u16;
typedef __attribute__((ext_vector_type(8))) __bf16 bf16x8;
typedef __attribute__((ext_vector_type(4))) float f32x4;

#define B_ 8
#define T_ 768
#define C_ 512
#define F_ 2048

__device__ __forceinline__ float b2f(u16 u) {
    union { float f; uint32_t i; } x; x.i = ((uint32_t)u) << 16; return x.f;
}
__device__ __forceinline__ u16 f2b(float f) {
    union { float f; uint32_t i; } x; x.f = f;
    return (u16)((x.i + 0x7fffu + ((x.i >> 16) & 1u)) >> 16);  // RNE
}

// ---------------------------------------------------------------------------
// GEMM: out[M,N] = A[M,K] @ Bt[N,K]^T (+f32 bias, epilogue). TM=128, BK=64.
// Swapped-operand MFMA; XOR-swizzled LDS. (Used for QKV / FFN1 — high wave
// count configs only.)
// ---------------------------------------------------------------------------
template <int TN, int EPI>
__global__ __launch_bounds__(128 * (TN / 64)) void gemm_bt(
    const u16* __restrict__ A, long long aB1, long long aB2, int aStride,
    const u16* __restrict__ Bt, long long bB1, long long bB2, int bStride,
    const float* __restrict__ bias,
    u16* __restrict__ out, long long oB1, long long oB2, int oStride,
    int K, float epiScale)
{
    constexpr int WN = TN / 64;
    constexpr int NT = 128 * WN;
    const int tid = threadIdx.x;
    const int wave = tid >> 6, lane = tid & 63;
    const int wm = wave & 1, wn = wave >> 1;
    const int quad = lane >> 4, l16 = lane & 15;
    const int zb = blockIdx.z >> 3, zh = blockIdx.z & 7;
    A   += (long long)zb * aB1 + (long long)zh * aB2;
    Bt  += (long long)zb * bB1 + (long long)zh * bB2;
    out += (long long)zb * oB1 + (long long)zh * oB2;
    const int m0 = blockIdx.x * 128;
    const int n0 = blockIdx.y * TN;

    __shared__ u16 As[128 * 64];
    __shared__ u16 Bs[TN * 64];

    const f32x4 vzero = {0.f, 0.f, 0.f, 0.f};
    f32x4 acc[4][4];
#pragma unroll
    for (int i = 0; i < 4; ++i)
#pragma unroll
        for (int j = 0; j < 4; ++j) acc[i][j] = vzero;

    for (int k0 = 0; k0 < K; k0 += 64) {
#pragma unroll
        for (int i = 0; i < 1024 / NT; ++i) {
            int c = tid + i * NT;
            int row = c >> 3, pc = c & 7, lc = pc ^ (row & 7);
            *(uint4*)&As[c * 8] =
                *(const uint4*)(A + (long long)(m0 + row) * aStride + (k0 + lc * 8));
        }
#pragma unroll
        for (int i = 0; i < (TN * 8) / NT; ++i) {
            int c = tid + i * NT;
            int row = c >> 3, pc = c & 7, lc = pc ^ (row & 7);
            *(uint4*)&Bs[c * 8] =
                *(const uint4*)(Bt + (long long)(n0 + row) * bStride + (k0 + lc * 8));
        }
        __syncthreads();
#pragma unroll
        for (int ks = 0; ks < 2; ++ks) {
            bf16x8 af[4], bfr[4];
#pragma unroll
            for (int mi = 0; mi < 4; ++mi) {
                int row = wm * 64 + mi * 16 + l16;
                int pc = ((ks << 2) | quad) ^ (row & 7);
                af[mi] = *(const bf16x8*)&As[row * 64 + pc * 8];
            }
#pragma unroll
            for (int ni = 0; ni < 4; ++ni) {
                int row = wn * 64 + ni * 16 + l16;
                int pc = ((ks << 2) | quad) ^ (row & 7);
                bfr[ni] = *(const bf16x8*)&Bs[row * 64 + pc * 8];
            }
#pragma unroll
            for (int mi = 0; mi < 4; ++mi)
#pragma unroll
                for (int ni = 0; ni < 4; ++ni)
                    acc[mi][ni] = __builtin_amdgcn_mfma_f32_16x16x32_bf16(
                        bfr[ni], af[mi], acc[mi][ni], 0, 0, 0);
        }
        __syncthreads();
    }

#pragma unroll
    for (int mi = 0; mi < 4; ++mi) {
        int row = m0 + wm * 64 + mi * 16 + l16;
#pragma unroll
        for (int ni = 0; ni < 4; ++ni) {
            int colb = n0 + wn * 64 + ni * 16 + quad * 4;
            u16 pk[4];
#pragma unroll
            for (int r = 0; r < 4; ++r) {
                float v = acc[mi][ni][r] + (bias ? bias[colb + r] : 0.f);
                if (EPI == 1) v = v > 0.f ? v : 0.f;
                if (EPI == 3) { if (colb + r < 512) v *= epiScale; }
                pk[r] = f2b(v);
            }
            uint2 p;
            p.x = (uint32_t)pk[0] | ((uint32_t)pk[1] << 16);
            p.y = (uint32_t)pk[2] | ((uint32_t)pk[3] << 16);
            *(uint2*)(out + (long long)row * oStride + colb) = p;
        }
    }
}

// ---------------------------------------------------------------------------
// gemm_bt4: small-tile GEMM for N=512 outputs (O-proj, FFN2).
// Block = 64x64 output, 256 threads, 4 waves (2x2), each wave 32x32 (acc[2][2]).
// Grid (M/64, N/64) = (96,8) -> 3072 waves = 12/CU. Reg-staged double buffer,
// one __syncthreads per K-step. LDS 32 KB.
// ---------------------------------------------------------------------------
template <int EPI>
__global__ __launch_bounds__(256) void gemm_bt4(
    const u16* __restrict__ A, int aStride,
    const u16* __restrict__ Bt, int bStride,
    const float* __restrict__ bias,
    u16* __restrict__ out, int oStride, int K)
{
    const int tid = threadIdx.x;
    const int wave = tid >> 6, lane = tid & 63;
    const int wm = wave & 1, wn = wave >> 1;
    const int quad = lane >> 4, l16 = lane & 15;
    const int m0 = blockIdx.x * 64;
    const int n0 = blockIdx.y * 64;

    __shared__ u16 As[2][64 * 64];
    __shared__ u16 Bs[2][64 * 64];

    const f32x4 vzero = {0.f, 0.f, 0.f, 0.f};
    f32x4 acc[2][2];
#pragma unroll
    for (int i = 0; i < 2; ++i)
#pragma unroll
        for (int j = 0; j < 2; ++j) acc[i][j] = vzero;

    // stage K-tile 0 into buffer 0
#pragma unroll
    for (int i = 0; i < 2; ++i) {
        int c = tid + i * 256;
        int row = c >> 3, pc = c & 7, lc = pc ^ (row & 7);
        *(uint4*)&As[0][c * 8] =
            *(const uint4*)(A + (long long)(m0 + row) * aStride + lc * 8);
        *(uint4*)&Bs[0][c * 8] =
            *(const uint4*)(Bt + (long long)(n0 + row) * bStride + lc * 8);
    }
    __syncthreads();

    int cb = 0;
    for (int k0 = 0; k0 < K; k0 += 64) {
        // issue next-tile loads early (latency hides under MFMA below)
        uint4 areg[2], breg[2];
        const bool pre = (k0 + 64 < K);
        if (pre) {
#pragma unroll
            for (int i = 0; i < 2; ++i) {
                int c = tid + i * 256;
                int row = c >> 3, pc = c & 7, lc = pc ^ (row & 7);
                areg[i] = *(const uint4*)(A + (long long)(m0 + row) * aStride
                                          + (k0 + 64 + lc * 8));
                breg[i] = *(const uint4*)(Bt + (long long)(n0 + row) * bStride
                                          + (k0 + 64 + lc * 8));
            }
        }
        __builtin_amdgcn_s_setprio(1);
#pragma unroll
        for (int ks = 0; ks < 2; ++ks) {
            bf16x8 af[2], bfr[2];
#pragma unroll
            for (int mi = 0; mi < 2; ++mi) {
                int row = wm * 32 + mi * 16 + l16;
                int pc = ((ks << 2) | quad) ^ (row & 7);
                af[mi] = *(const bf16x8*)&As[cb][row * 64 + pc * 8];
            }
#pragma unroll
            for (int ni = 0; ni < 2; ++ni) {
                int row = wn * 32 + ni * 16 + l16;
                int pc = ((ks << 2) | quad) ^ (row & 7);
                bfr[ni] = *(const bf16x8*)&Bs[cb][row * 64 + pc * 8];
            }
#pragma unroll
            for (int mi = 0; mi < 2; ++mi)
#pragma unroll
                for (int ni = 0; ni < 2; ++ni)
                    acc[mi][ni] = __builtin_amdgcn_mfma_f32_16x16x32_bf16(
                        bfr[ni], af[mi], acc[mi][ni], 0, 0, 0);
        }
        __builtin_amdgcn_s_setprio(0);
        if (pre) {
#pragma unroll
            for (int i = 0; i < 2; ++i) {
                int c = tid + i * 256;
                *(uint4*)&As[cb ^ 1][c * 8] = areg[i];
                *(uint4*)&Bs[cb ^ 1][c * 8] = breg[i];
            }
            __syncthreads();
            cb ^= 1;
        }
    }

#pragma unroll
    for (int mi = 0; mi < 2; ++mi) {
        int row = m0 + wm * 32 + mi * 16 + l16;
#pragma unroll
        for (int ni = 0; ni < 2; ++ni) {
            int colb = n0 + wn * 32 + ni * 16 + quad * 4;
            u16 pk[4];
#pragma unroll
            for (int r = 0; r < 4; ++r) {
                float v = acc[mi][ni][r] + bias[colb + r];
                if (EPI == 1) v = v > 0.f ? v : 0.f;
                pk[r] = f2b(v);
            }
            uint2 p;
            p.x = (uint32_t)pk[0] | ((uint32_t)pk[1] << 16);
            p.y = (uint32_t)pk[2] | ((uint32_t)pk[3] << 16);
            *(uint2*)(out + (long long)row * oStride + colb) = p;
        }
    }
}

// ---------------------------------------------------------------------------
// bandg[(t*8 + h)*9 + e] = q~[t,h,:] . erk[e,:]   (q pre-scaled by 1/8)
// ---------------------------------------------------------------------------
__global__ __launch_bounds__(256) void bandg_k(
    const u16* __restrict__ qkv, const float* __restrict__ erk,
    float* __restrict__ bandg)
{
    __shared__ float erkS[576];
    const int tid = threadIdx.x;
    for (int idx = tid; idx < 576; idx += 256) erkS[idx] = erk[idx];
    __syncthreads();
    const int gid = blockIdx.x * 256 + tid;       // 49152
    const int row = gid >> 3, h = gid & 7;
    const u16* q = qkv + (long long)row * 1536 + h * 64;
    float acc[9];
#pragma unroll
    for (int e = 0; e < 9; ++e) acc[e] = 0.f;
#pragma unroll
    for (int c = 0; c < 8; ++c) {
        uint4 d4 = *(const uint4*)(q + c * 8);
        const uint32_t dw[4] = {d4.x, d4.y, d4.z, d4.w};
#pragma unroll
        for (int j = 0; j < 8; ++j) {
            u16 uu = (u16)((dw[j >> 1] >> ((j & 1) * 16)) & 0xffff);
            float qv = b2f(uu);
            int d = c * 8 + j;
#pragma unroll
            for (int e = 0; e < 9; ++e) acc[e] += qv * erkS[e * 64 + d];
        }
    }
    float* o = bandg + (long long)gid * 9;
#pragma unroll
    for (int e = 0; e < 9; ++e) o[e] = acc[e];
}

// ---------------------------------------------------------------------------
// Flash attention v2 + R6 pipeline (unchanged from R6 — verified).
// ---------------------------------------------------------------------------
__global__ __launch_bounds__(256) void flash_attn(
    const u16* __restrict__ qkv, const u16* __restrict__ vt,
    const float* __restrict__ mask, const float* __restrict__ bandg,
    const float* __restrict__ erv, u16* __restrict__ outb)
{
    const int tid = threadIdx.x;
    const int w = tid >> 6, lane = tid & 63;
    const int quad = lane >> 4, l16 = lane & 15;
    const int orig = blockIdx.y * 12 + blockIdx.x;
    const int swz = (orig & 7) * 96 + (orig >> 3);
    const int qt = swz % 12, bh = swz / 12;
    const int b = bh >> 3, h = bh & 7;
    const int q0 = qt * 64;

    __shared__ u16 Ql[64 * 64];
    __shared__ u16 Kt[2][64 * 64];
    __shared__ u16 Vt[2][64 * 64];
    __shared__ u16 Pl[4][16 * 64];
    __shared__ float bandk[64][10];
    __shared__ float maskK[2][64];

#pragma unroll
    for (int i = 0; i < 2; ++i) {
        int c = tid + i * 256;
        int r = c >> 3, pc = c & 7, lc = pc ^ (r & 7);
        *(uint4*)&Ql[c * 8] =
            *(const uint4*)(qkv + (long long)(b * T_ + q0 + r) * 1536 + h * 64 + lc * 8);
    }
#pragma unroll
    for (int i = 0; i < 2; ++i) {
        int c = tid + i * 256;
        int r = c >> 3, pc = c & 7, lc = pc ^ (r & 7);
        *(uint4*)&Kt[0][c * 8] =
            *(const uint4*)(qkv + (long long)(b * T_ + r) * 1536 + 512 + h * 64 + lc * 8);
        *(uint4*)&Vt[0][c * 8] =
            *(const uint4*)(vt + ((long long)bh * 64 + r) * T_ + lc * 8);
    }
    if (tid < 64) maskK[0][tid] = mask[b * T_ + tid];
    for (int idx = tid; idx < 576; idx += 256) {
        int r = idx / 9, e = idx - r * 9;
        bandk[r][e] = bandg[((long long)(b * T_ + q0 + r) * 8 + h) * 9 + e];
    }

    const int i_row = q0 + w * 16 + l16;
    const float mi = mask[b * T_ + i_row];
    float m_run = -1e30f, l_run = 0.f;
    const f32x4 vzero = {0.f, 0.f, 0.f, 0.f};
    f32x4 vacc[4] = {vzero, vzero, vzero, vzero};
    float pb[3] = {0.f, 0.f, 0.f};

    __syncthreads();
    bf16x8 qf[2];
#pragma unroll
    for (int ks = 0; ks < 2; ++ks) {
        int r = w * 16 + l16;
        int pc = ((ks << 2) | quad) ^ (r & 7);
        qf[ks] = *(const bf16x8*)&Ql[r * 64 + pc * 8];
    }

    int cbuf = 0;
    for (int kt = 0; kt < 12; ++kt) {
        uint4 kreg[2], vreg[2];
        float mreg = 0.f;
        const bool pre = (kt < 11);
        if (pre) {
            const int ktn = kt + 1;
#pragma unroll
            for (int i = 0; i < 2; ++i) {
                int c = tid + i * 256;
                int r = c >> 3, pc = c & 7, lc = pc ^ (r & 7);
                kreg[i] = *(const uint4*)(qkv + (long long)(b * T_ + ktn * 64 + r) * 1536
                                          + 512 + h * 64 + lc * 8);
                vreg[i] = *(const uint4*)(vt + ((long long)bh * 64 + r) * T_
                                          + ktn * 64 + lc * 8);
            }
            if (tid < 64) mreg = mask[b * T_ + ktn * 64 + tid];
        }

        const float mkv = maskK[cbuf][lane];
        const bool tile_clean = (__ballot(mkv == 0.f) == 0ull);
        const bool fast = tile_clean && (mi != 0.f);
        const bool has_band = (kt * 64 <= q0 + w * 16 + 19) &&
                              (kt * 64 + 67 >= q0 + w * 16);

        f32x4 sacc[4];
#pragma unroll
        for (int ni = 0; ni < 4; ++ni) sacc[ni] = vzero;
        __builtin_amdgcn_s_setprio(1);
#pragma unroll
        for (int ks = 0; ks < 2; ++ks)
#pragma unroll
            for (int ni = 0; ni < 4; ++ni) {
                int r = ni * 16 + l16;
                int pc = ((ks << 2) | quad) ^ (r & 7);
                bf16x8 kf = *(const bf16x8*)&Kt[cbuf][r * 64 + pc * 8];
                sacc[ni] = __builtin_amdgcn_mfma_f32_16x16x32_bf16(kf, qf[ks], sacc[ni], 0, 0, 0);
            }
        __builtin_amdgcn_s_setprio(0);

        if (has_band) {
#pragma unroll
            for (int ni = 0; ni < 4; ++ni)
#pragma unroll
                for (int r = 0; r < 4; ++r) {
                    int jl = ni * 16 + quad * 4 + r;
                    int dlt = kt * 64 + jl - i_row;
                    if (dlt >= -4 && dlt <= 4)
                        sacc[ni][r] += bandk[w * 16 + l16][dlt + 4];
                }
        }
        if (!fast) {
#pragma unroll
            for (int ni = 0; ni < 4; ++ni)
#pragma unroll
                for (int r = 0; r < 4; ++r) {
                    int jl = ni * 16 + quad * 4 + r;
                    if (mi * maskK[cbuf][jl] == 0.f) sacc[ni][r] = -10000.0f;
                }
        }

        float mx = -1e30f;
#pragma unroll
        for (int ni = 0; ni < 4; ++ni)
#pragma unroll
            for (int r = 0; r < 4; ++r) mx = fmaxf(mx, sacc[ni][r]);
        mx = fmaxf(mx, __shfl_xor(mx, 16));
        mx = fmaxf(mx, __shfl_xor(mx, 32));
        float m_new = fmaxf(m_run, mx);
        float alpha = __expf(m_run - m_new);
        m_run = m_new;
        l_run *= alpha;
#pragma unroll
        for (int ni = 0; ni < 4; ++ni) vacc[ni] = vacc[ni] * alpha;
#pragma unroll
        for (int k = 0; k < 3; ++k) pb[k] *= alpha;

        float lsum = 0.f;
#pragma unroll
        for (int ni = 0; ni < 4; ++ni) {
            u16 pk[4];
#pragma unroll
            for (int r = 0; r < 4; ++r) {
                float u = __expf(sacc[ni][r] - m_new);
                lsum += u;
                pk[r] = f2b(u);
            }
            int c0 = ni * 16 + quad * 4;
            int phys = (((c0 >> 3) ^ (l16 & 7)) << 3) + (c0 & 7);
            uint2 p;
            p.x = (uint32_t)pk[0] | ((uint32_t)pk[1] << 16);
            p.y = (uint32_t)pk[2] | ((uint32_t)pk[3] << 16);
            *(uint2*)&Pl[w][l16 * 64 + phys] = p;
        }
        l_run += lsum;

        if (has_band) {
#pragma unroll
            for (int k = 0; k < 3; ++k) {
                int e = quad * 3 + k;
                if (e < 9) {
                    int jl = i_row + e - 4 - kt * 64;
                    if (jl >= 0 && jl < 64) {
                        int phys = (((jl >> 3) ^ (l16 & 7)) << 3) + (jl & 7);
                        pb[k] += b2f(Pl[w][l16 * 64 + phys]);
                    }
                }
            }
        }

        __builtin_amdgcn_s_setprio(1);
#pragma unroll
        for (int ks = 0; ks < 2; ++ks) {
            int pcc = ((ks << 2) | quad) ^ (l16 & 7);
            bf16x8 pf = *(const bf16x8*)&Pl[w][l16 * 64 + pcc * 8];
#pragma unroll
            for (int ni = 0; ni < 4; ++ni) {
                int r = ni * 16 + l16;
                int pc = ((ks << 2) | quad) ^ (r & 7);
                bf16x8 vf = *(const bf16x8*)&Vt[cbuf][r * 64 + pc * 8];
                vacc[ni] = __builtin_amdgcn_mfma_f32_16x16x32_bf16(vf, pf, vacc[ni], 0, 0, 0);
            }
        }
        __builtin_amdgcn_s_setprio(0);

        if (pre) {
#pragma unroll
            for (int i = 0; i < 2; ++i) {
                int c = tid + i * 256;
                *(uint4*)&Kt[cbuf ^ 1][c * 8] = kreg[i];
                *(uint4*)&Vt[cbuf ^ 1][c * 8] = vreg[i];
            }
            if (tid < 64) maskK[cbuf ^ 1][tid] = mreg;
            __syncthreads();
            cbuf ^= 1;
        }
    }

    l_run += __shfl_xor(l_run, 16);
    l_run += __shfl_xor(l_run, 32);
    const float rinv = 1.f / l_run;

    float pband[9];
#pragma unroll
    for (int e = 0; e < 9; ++e) {
        float val = (quad == e / 3) ? pb[e % 3] : 0.f;
        val += __shfl_xor(val, 16);
        val += __shfl_xor(val, 32);
        pband[e] = val * rinv;
    }

    u16* orow = outb + (long long)(b * T_ + i_row) * C_ + h * 64;
#pragma unroll
    for (int ni = 0; ni < 4; ++ni) {
        u16 pk[4];
#pragma unroll
        for (int r = 0; r < 4; ++r) {
            int d = ni * 16 + quad * 4 + r;
            float v = vacc[ni][r] * rinv;
#pragma unroll
            for (int e = 0; e < 9; ++e) v += pband[e] * erv[e * 64 + d];
            pk[r] = f2b(v);
        }
        uint2 p;
        p.x = (uint32_t)pk[0] | ((uint32_t)pk[1] << 16);
        p.y = (uint32_t)pk[2] | ((uint32_t)pk[3] << 16);
        *(uint2*)(orow + ni * 16 + quad * 4) = p;
    }
}

// ---------------------------------------------------------------------------
// One-time weight transposes (f32 -> bf16), batched over layers.
// ---------------------------------------------------------------------------
__global__ void transpose_qkvo(const float* __restrict__ Wq, const float* __restrict__ Wk,
                               const float* __restrict__ Wv, const float* __restrict__ Wo,
                               u16* __restrict__ wqkvT, u16* __restrict__ woT)
{
    __shared__ u16 tile[32][33];
    const int z = blockIdx.z, l = z >> 2, which = z & 3;
    const float* src = (which == 0 ? Wq : which == 1 ? Wk : which == 2 ? Wv : Wo)
                       + (long long)l * 262144;
    u16* dst = (which == 3) ? woT + (long long)l * 262144
                            : wqkvT + (long long)l * 786432 + which * 262144;
    const int r0 = blockIdx.y * 32, c0 = blockIdx.x * 32;
    const int tx = threadIdx.x, ty = threadIdx.y;
#pragma unroll
    for (int i = 0; i < 32; i += 8)
        tile[ty + i][tx] = f2b(src[(long long)(r0 + ty + i) * 512 + (c0 + tx)]);
    __syncthreads();
#pragma unroll
    for (int i = 0; i < 32; i += 8)
        dst[(long long)(c0 + ty + i) * 512 + (r0 + tx)] = tile[tx][ty + i];
}

__global__ void transpose_f2bL(const float* __restrict__ src0, int sStride, long long sLayer,
                               u16* __restrict__ dst0, int dStride, long long dLayer)
{
    __shared__ u16 tile[32][33];
    const int l = blockIdx.z;
    const float* src = src0 + (long long)l * sLayer;
    u16* dst = dst0 + (long long)l * dLayer;
    const int r0 = blockIdx.y * 32, c0 = blockIdx.x * 32;
    const int tx = threadIdx.x, ty = threadIdx.y;
#pragma unroll
    for (int i = 0; i < 32; i += 8)
        tile[ty + i][tx] = f2b(src[(long long)(r0 + ty + i) * sStride + (c0 + tx)]);
    __syncthreads();
#pragma unroll
    for (int i = 0; i < 32; i += 8)
        dst[(long long)(c0 + ty + i) * dStride + (r0 + tx)] = tile[tx][ty + i];
}

__global__ void transpose_b(const u16* __restrict__ src, long long sB1, long long sB2, int sStride,
                            u16* __restrict__ dst, long long dB1, long long dB2, int dStride)
{
    __shared__ u16 tile[32][33];
    const int z = blockIdx.z, zb = z >> 3, zh = z & 7;
    src += (long long)zb * sB1 + (long long)zh * sB2;
    dst += (long long)zb * dB1 + (long long)zh * dB2;
    const int r0 = blockIdx.y * 32, c0 = blockIdx.x * 32;
    const int tx = threadIdx.x, ty = threadIdx.y;
#pragma unroll
    for (int i = 0; i < 32; i += 8)
        tile[ty + i][tx] = src[(long long)(r0 + ty + i) * sStride + (c0 + tx)];
    __syncthreads();
#pragma unroll
    for (int i = 0; i < 32; i += 8)
        dst[(long long)(c0 + ty + i) * dStride + (r0 + tx)] = tile[tx][ty + i];
}

__global__ void concat_bias(const float* __restrict__ bq, const float* __restrict__ bk,
                            const float* __restrict__ bv, float* __restrict__ dst)
{
    int i = blockIdx.x * 256 + threadIdx.x;
    int l = i / 1536, n = i - l * 1536;
    float v = (n < 512) ? bq[l * 512 + n]
             : (n < 1024 ? bk[l * 512 + (n - 512)] : bv[l * 512 + (n - 1024)]);
    dst[i] = v;
}

__global__ void mask_in(const float* __restrict__ x, const float* __restrict__ mask,
                        u16* __restrict__ out)
{
    int i4 = (blockIdx.x * 256 + threadIdx.x) * 4;
    float4 xv = *(const float4*)(x + i4);
    float m = mask[i4 >> 9];
    u16 pk[4] = {f2b(xv.x * m), f2b(xv.y * m), f2b(xv.z * m), f2b(xv.w * m)};
    uint2 p; p.x = (uint32_t)pk[0] | ((uint32_t)pk[1] << 16);
    p.y = (uint32_t)pk[2] | ((uint32_t)pk[3] << 16);
    *(uint2*)(out + i4) = p;
}

__global__ void mask_out(const u16* __restrict__ x, const float* __restrict__ mask,
                         float* __restrict__ out)
{
    int i4 = (blockIdx.x * 256 + threadIdx.x) * 4;
    uint2 p = *(const uint2*)(x + i4);
    float m = mask[i4 >> 9];
    float4 o;
    o.x = b2f((u16)(p.x & 0xffff)) * m;
    o.y = b2f((u16)(p.x >> 16)) * m;
    o.z = b2f((u16)(p.y & 0xffff)) * m;
    o.w = b2f((u16)(p.y >> 16)) * m;
    *(float4*)(out + i4) = o;
}

__global__ __launch_bounds__(256) void add_ln(
    const u16* __restrict__ x, const u16* __restrict__ y,
    const float* __restrict__ sc, const float* __restrict__ bi,
    u16* __restrict__ outx)
{
    const int wave = threadIdx.x >> 6, lane = threadIdx.x & 63;
    const long long r = (long long)blockIdx.x * 4 + wave;
    const u16* xr = x + r * C_;
    const u16* yr = y + r * C_;
    float v[8], s = 0.f;
#pragma unroll
    for (int it = 0; it < 2; ++it) {
        int j0 = it * 256 + lane * 4;
        uint2 px = *(const uint2*)(xr + j0);
        uint2 py = *(const uint2*)(yr + j0);
        v[it * 4 + 0] = b2f((u16)(px.x & 0xffff)) + b2f((u16)(py.x & 0xffff));
        v[it * 4 + 1] = b2f((u16)(px.x >> 16))    + b2f((u16)(py.x >> 16));
        v[it * 4 + 2] = b2f((u16)(px.y & 0xffff)) + b2f((u16)(py.y & 0xffff));
        v[it * 4 + 3] = b2f((u16)(px.y >> 16))    + b2f((u16)(py.y >> 16));
        s += v[it * 4 + 0] + v[it * 4 + 1] + v[it * 4 + 2] + v[it * 4 + 3];
    }
#pragma unroll
    for (int off = 32; off > 0; off >>= 1) s += __shfl_down(s, off);
    s = __shfl(s, 0);
    const float mean = s * (1.f / 512.f);
    float var = 0.f;
#pragma unroll
    for (int l = 0; l < 8; ++l) { float d = v[l] - mean; var += d * d; }
#pragma unroll
    for (int off = 32; off > 0; off >>= 1) var += __shfl_down(var, off);
    var = __shfl(var, 0);
    const float rs = rsqrtf(var * (1.f / 512.f) + 1e-6f);
    u16* orow = outx + r * C_;
#pragma unroll
    for (int it = 0; it < 2; ++it) {
        int j0 = it * 256 + lane * 4;
        float4 s4 = *(const float4*)(sc + j0);
        float4 b4 = *(const float4*)(bi + j0);
        u16 pk[4];
        pk[0] = f2b((v[it * 4 + 0] - mean) * rs * s4.x + b4.x);
        pk[1] = f2b((v[it * 4 + 1] - mean) * rs * s4.y + b4.y);
        pk[2] = f2b((v[it * 4 + 2] - mean) * rs * s4.z + b4.z);
        pk[3] = f2b((v[it * 4 + 3] - mean) * rs * s4.w + b4.w);
        uint2 p; p.x = (uint32_t)pk[0] | ((uint32_t)pk[1] << 16);
        p.y = (uint32_t)pk[2] | ((uint32_t)pk[3] << 16);
        *(uint2*)(orow + j0) = p;
    }
}

// ===========================================================================
extern "C" void kernel_launch(void* const* d_in, const int* in_sizes, int n_in,
                              void* d_out, int out_size, void* d_ws, size_t ws_size,
                              hipStream_t stream)
{
    const float* x    = (const float*)d_in[0];
    const float* mask = (const float*)d_in[1];
    const float* Wq   = (const float*)d_in[2];
    const float* bq   = (const float*)d_in[3];
    const float* Wk   = (const float*)d_in[4];
    const float* bk   = (const float*)d_in[5];
    const float* Wv   = (const float*)d_in[6];
    const float* bv   = (const float*)d_in[7];
    const float* Wo   = (const float*)d_in[8];
    const float* bo   = (const float*)d_in[9];
    const float* erk  = (const float*)d_in[10];
    const float* erv  = (const float*)d_in[11];
    const float* ln1s = (const float*)d_in[12];
    const float* ln1b = (const float*)d_in[13];
    const float* W1   = (const float*)d_in[14];
    const float* b1   = (const float*)d_in[15];
    const float* W2   = (const float*)d_in[16];
    const float* b2   = (const float*)d_in[17];
    const float* ln2s = (const float*)d_in[18];
    const float* ln2b = (const float*)d_in[19];
    float* out = (float*)d_out;
    u16* ws  = (u16*)d_ws;

    const long long CF = 512LL * 2048;
    const int M = B_ * T_;  // 6144

    // ws layout (u16 units). Total 51,234,816 u16 = 102.5 MB (<121.7 MB proven).
    u16* wqkvT   = ws;                      // [6][1536][512]
    u16* woT     = ws + 4718592;            // [6][512][512]
    u16* w1T     = ws + 6291456;            // [6][2048][512]
    u16* w2T     = ws + 12582912;           // [6][512][2048]
    float* bqkv  = (float*)(ws + 18874368); // [6][1536] f32
    u16* xb      = ws + 18892800;           // [M][512]
    u16* qkvb    = ws + 22038528;           // [M][1536]
    u16* vtb     = ws + 31475712;           // [64][64][768]; aliased as yb
    u16* attnb   = ws + 34621440;           // [M][512]
    u16* scr     = ws + 37767168;           // h1 [M][2048]
    float* bandg = (float*)(ws + 50350080); // [M][8][9] f32
    u16* yb      = vtb;

    const dim3 tb(32, 8);

    // --- one-time prologue ---
    transpose_qkvo<<<dim3(16, 16, 24), tb, 0, stream>>>(Wq, Wk, Wv, Wo, wqkvT, woT);
    transpose_f2bL<<<dim3(64, 16, 6), tb, 0, stream>>>(W1, 2048, CF, w1T, 512, 1048576);
    transpose_f2bL<<<dim3(16, 64, 6), tb, 0, stream>>>(W2, 512,  CF, w2T, 2048, 1048576);
    concat_bias<<<36, 256, 0, stream>>>(bq, bk, bv, bqkv);
    mask_in<<<(M * 512) / 1024, 256, 0, stream>>>(x, mask, xb);

    for (int l = 0; l < 6; ++l) {
        // QKV: [6144,512] @ [1536,512]^T; q *= 1/8 in epilogue
        gemm_bt<128, 3><<<dim3(48, 12, 1), 256, 0, stream>>>(
            xb, 0, 0, 512, wqkvT + (long long)l * 786432, 0, 0, 512, bqkv + l * 1536,
            qkvb, 0, 0, 1536, 512, 0.125f);
        // bandk table for this layer
        bandg_k<<<192, 256, 0, stream>>>(qkvb, erk + l * 576, bandg);
        // V^T per head: [64][768]
        transpose_b<<<dim3(2, 24, 64), tb, 0, stream>>>(
            qkvb + 1024, 768LL * 1536, 64, 1536,
            vtb, 8LL * 64 * 768, 64LL * 768, 768);
        // fused attention -> attnb
        flash_attn<<<dim3(12, 64), 256, 0, stream>>>(
            qkvb, vtb, mask, bandg, erv + l * 576, attnb);
        // O projection -> yb (=vtb, dead now): small-tile high-occupancy GEMM
        gemm_bt4<0><<<dim3(96, 8), 256, 0, stream>>>(
            attnb, 512, woT + (long long)l * 262144, 512, bo + l * 512,
            yb, 512, 512);
        add_ln<<<1536, 256, 0, stream>>>(xb, yb, ln1s + l * 512, ln1b + l * 512, xb);
        // FFN
        gemm_bt<128, 1><<<dim3(48, 16, 1), 256, 0, stream>>>(
            xb, 0, 0, 512, w1T + (long long)l * 1048576, 0, 0, 512, b1 + l * 2048,
            scr, 0, 0, 2048, 512, 0.f);
        gemm_bt4<0><<<dim3(96, 8), 256, 0, stream>>>(
            scr, 2048, w2T + (long long)l * 1048576, 2048, b2 + l * 512,
            yb, 512, 2048);
        add_ln<<<1536, 256, 0, stream>>>(xb, yb, ln2s + l * 512, ln2b + l * 512, xb);
    }

    mask_out<<<(M * 512) / 1024, 256, 0, stream>>>(xb, mask, out);
}

// Round 4
// 1008.982 us; speedup vs baseline: 1.5543x; 1.5543x over previous
//
#include <hip/hip_runtime.h>
#include <stdint.h>

// ============================================================================
// Encoder (6-layer rel-pos transformer), MI355X. f32 in/out, bf16 internals.
// R9: gemm_bt4 de-risked — R7's reg-staged dbuf spilled (88 MB scratch);
// R8's global_load_lds build died with no counters (possible DMA hang).
// This version uses ONLY the staging idiom already verified in gemm_bt
// (same-iteration global->LDS uint4 store, two barriers per K-step) at
// 64x64 / 4-wave geometry: 768 blocks x 4 waves = 12 waves/CU (vs 3) for
// the N=512 GEMMs (O-proj, FFN2). LDS 16 KB. Zero new codegen constructs.
// ============================================================================

typedef unsigned short u16;
typedef __attribute__((ext_vector_type(8))) __bf16 bf16x8;
typedef __attribute__((ext_vector_type(4))) float f32x4;

#define B_ 8
#define T_ 768
#define C_ 512
#define F_ 2048

__device__ __forceinline__ float b2f(u16 u) {
    union { float f; uint32_t i; } x; x.i = ((uint32_t)u) << 16; return x.f;
}
__device__ __forceinline__ u16 f2b(float f) {
    union { float f; uint32_t i; } x; x.f = f;
    return (u16)((x.i + 0x7fffu + ((x.i >> 16) & 1u)) >> 16);  // RNE
}

// ---------------------------------------------------------------------------
// GEMM: out[M,N] = A[M,K] @ Bt[N,K]^T (+f32 bias, epilogue). TM=128, BK=64.
// Swapped-operand MFMA; XOR-swizzled LDS. (QKV / FFN1 — unchanged, verified.)
// ---------------------------------------------------------------------------
template <int TN, int EPI>
__global__ __launch_bounds__(128 * (TN / 64)) void gemm_bt(
    const u16* __restrict__ A, long long aB1, long long aB2, int aStride,
    const u16* __restrict__ Bt, long long bB1, long long bB2, int bStride,
    const float* __restrict__ bias,
    u16* __restrict__ out, long long oB1, long long oB2, int oStride,
    int K, float epiScale)
{
    constexpr int WN = TN / 64;
    constexpr int NT = 128 * WN;
    const int tid = threadIdx.x;
    const int wave = tid >> 6, lane = tid & 63;
    const int wm = wave & 1, wn = wave >> 1;
    const int quad = lane >> 4, l16 = lane & 15;
    const int zb = blockIdx.z >> 3, zh = blockIdx.z & 7;
    A   += (long long)zb * aB1 + (long long)zh * aB2;
    Bt  += (long long)zb * bB1 + (long long)zh * bB2;
    out += (long long)zb * oB1 + (long long)zh * oB2;
    const int m0 = blockIdx.x * 128;
    const int n0 = blockIdx.y * TN;

    __shared__ u16 As[128 * 64];
    __shared__ u16 Bs[TN * 64];

    const f32x4 vzero = {0.f, 0.f, 0.f, 0.f};
    f32x4 acc[4][4];
#pragma unroll
    for (int i = 0; i < 4; ++i)
#pragma unroll
        for (int j = 0; j < 4; ++j) acc[i][j] = vzero;

    for (int k0 = 0; k0 < K; k0 += 64) {
#pragma unroll
        for (int i = 0; i < 1024 / NT; ++i) {
            int c = tid + i * NT;
            int row = c >> 3, pc = c & 7, lc = pc ^ (row & 7);
            *(uint4*)&As[c * 8] =
                *(const uint4*)(A + (long long)(m0 + row) * aStride + (k0 + lc * 8));
        }
#pragma unroll
        for (int i = 0; i < (TN * 8) / NT; ++i) {
            int c = tid + i * NT;
            int row = c >> 3, pc = c & 7, lc = pc ^ (row & 7);
            *(uint4*)&Bs[c * 8] =
                *(const uint4*)(Bt + (long long)(n0 + row) * bStride + (k0 + lc * 8));
        }
        __syncthreads();
#pragma unroll
        for (int ks = 0; ks < 2; ++ks) {
            bf16x8 af[4], bfr[4];
#pragma unroll
            for (int mi = 0; mi < 4; ++mi) {
                int row = wm * 64 + mi * 16 + l16;
                int pc = ((ks << 2) | quad) ^ (row & 7);
                af[mi] = *(const bf16x8*)&As[row * 64 + pc * 8];
            }
#pragma unroll
            for (int ni = 0; ni < 4; ++ni) {
                int row = wn * 64 + ni * 16 + l16;
                int pc = ((ks << 2) | quad) ^ (row & 7);
                bfr[ni] = *(const bf16x8*)&Bs[row * 64 + pc * 8];
            }
#pragma unroll
            for (int mi = 0; mi < 4; ++mi)
#pragma unroll
                for (int ni = 0; ni < 4; ++ni)
                    acc[mi][ni] = __builtin_amdgcn_mfma_f32_16x16x32_bf16(
                        bfr[ni], af[mi], acc[mi][ni], 0, 0, 0);
        }
        __syncthreads();
    }

#pragma unroll
    for (int mi = 0; mi < 4; ++mi) {
        int row = m0 + wm * 64 + mi * 16 + l16;
#pragma unroll
        for (int ni = 0; ni < 4; ++ni) {
            int colb = n0 + wn * 64 + ni * 16 + quad * 4;
            u16 pk[4];
#pragma unroll
            for (int r = 0; r < 4; ++r) {
                float v = acc[mi][ni][r] + (bias ? bias[colb + r] : 0.f);
                if (EPI == 1) v = v > 0.f ? v : 0.f;
                if (EPI == 3) { if (colb + r < 512) v *= epiScale; }
                pk[r] = f2b(v);
            }
            uint2 p;
            p.x = (uint32_t)pk[0] | ((uint32_t)pk[1] << 16);
            p.y = (uint32_t)pk[2] | ((uint32_t)pk[3] << 16);
            *(uint2*)(out + (long long)row * oStride + colb) = p;
        }
    }
}

// ---------------------------------------------------------------------------
// gemm_bt4: small-tile GEMM for N=512 outputs (O-proj, FFN2).
// Block = 64x64 output, 256 threads, 4 waves (2x2), each wave 32x32.
// Staging idiom IDENTICAL to gemm_bt (same-iteration uint4 global->LDS,
// two barriers per K-step) — proven no-spill codegen. 768 blocks x 4 waves
// = 12 waves/CU; 3 blocks/CU co-resident overlap staging vs MFMA.
// ---------------------------------------------------------------------------
template <int EPI>
__global__ __launch_bounds__(256) void gemm_bt4(
    const u16* __restrict__ A, int aStride,
    const u16* __restrict__ Bt, int bStride,
    const float* __restrict__ bias,
    u16* __restrict__ out, int oStride, int K)
{
    const int tid = threadIdx.x;
    const int wave = tid >> 6, lane = tid & 63;
    const int wm = wave & 1, wn = wave >> 1;
    const int quad = lane >> 4, l16 = lane & 15;
    const int m0 = blockIdx.x * 64;
    const int n0 = blockIdx.y * 64;

    __shared__ u16 As[64 * 64];
    __shared__ u16 Bs[64 * 64];

    const f32x4 vzero = {0.f, 0.f, 0.f, 0.f};
    f32x4 acc[2][2];
#pragma unroll
    for (int i = 0; i < 2; ++i)
#pragma unroll
        for (int j = 0; j < 2; ++j) acc[i][j] = vzero;

    for (int k0 = 0; k0 < K; k0 += 64) {
#pragma unroll
        for (int i = 0; i < 2; ++i) {
            int c = tid + i * 256;
            int row = c >> 3, pc = c & 7, lc = pc ^ (row & 7);
            *(uint4*)&As[c * 8] =
                *(const uint4*)(A + (long long)(m0 + row) * aStride + (k0 + lc * 8));
            *(uint4*)&Bs[c * 8] =
                *(const uint4*)(Bt + (long long)(n0 + row) * bStride + (k0 + lc * 8));
        }
        __syncthreads();
        __builtin_amdgcn_s_setprio(1);
#pragma unroll
        for (int ks = 0; ks < 2; ++ks) {
            bf16x8 af[2], bfr[2];
#pragma unroll
            for (int mi = 0; mi < 2; ++mi) {
                int row = wm * 32 + mi * 16 + l16;
                int pc = ((ks << 2) | quad) ^ (row & 7);
                af[mi] = *(const bf16x8*)&As[row * 64 + pc * 8];
            }
#pragma unroll
            for (int ni = 0; ni < 2; ++ni) {
                int row = wn * 32 + ni * 16 + l16;
                int pc = ((ks << 2) | quad) ^ (row & 7);
                bfr[ni] = *(const bf16x8*)&Bs[row * 64 + pc * 8];
            }
#pragma unroll
            for (int mi = 0; mi < 2; ++mi)
#pragma unroll
                for (int ni = 0; ni < 2; ++ni)
                    acc[mi][ni] = __builtin_amdgcn_mfma_f32_16x16x32_bf16(
                        bfr[ni], af[mi], acc[mi][ni], 0, 0, 0);
        }
        __builtin_amdgcn_s_setprio(0);
        __syncthreads();
    }

#pragma unroll
    for (int mi = 0; mi < 2; ++mi) {
        int row = m0 + wm * 32 + mi * 16 + l16;
#pragma unroll
        for (int ni = 0; ni < 2; ++ni) {
            int colb = n0 + wn * 32 + ni * 16 + quad * 4;
            u16 pk[4];
#pragma unroll
            for (int r = 0; r < 4; ++r) {
                float v = acc[mi][ni][r] + bias[colb + r];
                if (EPI == 1) v = v > 0.f ? v : 0.f;
                pk[r] = f2b(v);
            }
            uint2 p;
            p.x = (uint32_t)pk[0] | ((uint32_t)pk[1] << 16);
            p.y = (uint32_t)pk[2] | ((uint32_t)pk[3] << 16);
            *(uint2*)(out + (long long)row * oStride + colb) = p;
        }
    }
}

// ---------------------------------------------------------------------------
// bandg[(t*8 + h)*9 + e] = q~[t,h,:] . erk[e,:]   (q pre-scaled by 1/8)
// ---------------------------------------------------------------------------
__global__ __launch_bounds__(256) void bandg_k(
    const u16* __restrict__ qkv, const float* __restrict__ erk,
    float* __restrict__ bandg)
{
    __shared__ float erkS[576];
    const int tid = threadIdx.x;
    for (int idx = tid; idx < 576; idx += 256) erkS[idx] = erk[idx];
    __syncthreads();
    const int gid = blockIdx.x * 256 + tid;       // 49152
    const int row = gid >> 3, h = gid & 7;
    const u16* q = qkv + (long long)row * 1536 + h * 64;
    float acc[9];
#pragma unroll
    for (int e = 0; e < 9; ++e) acc[e] = 0.f;
#pragma unroll
    for (int c = 0; c < 8; ++c) {
        uint4 d4 = *(const uint4*)(q + c * 8);
        const uint32_t dw[4] = {d4.x, d4.y, d4.z, d4.w};
#pragma unroll
        for (int j = 0; j < 8; ++j) {
            u16 uu = (u16)((dw[j >> 1] >> ((j & 1) * 16)) & 0xffff);
            float qv = b2f(uu);
            int d = c * 8 + j;
#pragma unroll
            for (int e = 0; e < 9; ++e) acc[e] += qv * erkS[e * 64 + d];
        }
    }
    float* o = bandg + (long long)gid * 9;
#pragma unroll
    for (int e = 0; e < 9; ++e) o[e] = acc[e];
}

// ---------------------------------------------------------------------------
// Flash attention v2 + R6 pipeline (unchanged — verified).
// ---------------------------------------------------------------------------
__global__ __launch_bounds__(256) void flash_attn(
    const u16* __restrict__ qkv, const u16* __restrict__ vt,
    const float* __restrict__ mask, const float* __restrict__ bandg,
    const float* __restrict__ erv, u16* __restrict__ outb)
{
    const int tid = threadIdx.x;
    const int w = tid >> 6, lane = tid & 63;
    const int quad = lane >> 4, l16 = lane & 15;
    const int orig = blockIdx.y * 12 + blockIdx.x;
    const int swz = (orig & 7) * 96 + (orig >> 3);
    const int qt = swz % 12, bh = swz / 12;
    const int b = bh >> 3, h = bh & 7;
    const int q0 = qt * 64;

    __shared__ u16 Ql[64 * 64];
    __shared__ u16 Kt[2][64 * 64];
    __shared__ u16 Vt[2][64 * 64];
    __shared__ u16 Pl[4][16 * 64];
    __shared__ float bandk[64][10];
    __shared__ float maskK[2][64];

#pragma unroll
    for (int i = 0; i < 2; ++i) {
        int c = tid + i * 256;
        int r = c >> 3, pc = c & 7, lc = pc ^ (r & 7);
        *(uint4*)&Ql[c * 8] =
            *(const uint4*)(qkv + (long long)(b * T_ + q0 + r) * 1536 + h * 64 + lc * 8);
    }
#pragma unroll
    for (int i = 0; i < 2; ++i) {
        int c = tid + i * 256;
        int r = c >> 3, pc = c & 7, lc = pc ^ (r & 7);
        *(uint4*)&Kt[0][c * 8] =
            *(const uint4*)(qkv + (long long)(b * T_ + r) * 1536 + 512 + h * 64 + lc * 8);
        *(uint4*)&Vt[0][c * 8] =
            *(const uint4*)(vt + ((long long)bh * 64 + r) * T_ + lc * 8);
    }
    if (tid < 64) maskK[0][tid] = mask[b * T_ + tid];
    for (int idx = tid; idx < 576; idx += 256) {
        int r = idx / 9, e = idx - r * 9;
        bandk[r][e] = bandg[((long long)(b * T_ + q0 + r) * 8 + h) * 9 + e];
    }

    const int i_row = q0 + w * 16 + l16;
    const float mi = mask[b * T_ + i_row];
    float m_run = -1e30f, l_run = 0.f;
    const f32x4 vzero = {0.f, 0.f, 0.f, 0.f};
    f32x4 vacc[4] = {vzero, vzero, vzero, vzero};
    float pb[3] = {0.f, 0.f, 0.f};

    __syncthreads();
    bf16x8 qf[2];
#pragma unroll
    for (int ks = 0; ks < 2; ++ks) {
        int r = w * 16 + l16;
        int pc = ((ks << 2) | quad) ^ (r & 7);
        qf[ks] = *(const bf16x8*)&Ql[r * 64 + pc * 8];
    }

    int cbuf = 0;
    for (int kt = 0; kt < 12; ++kt) {
        uint4 kreg[2], vreg[2];
        float mreg = 0.f;
        const bool pre = (kt < 11);
        if (pre) {
            const int ktn = kt + 1;
#pragma unroll
            for (int i = 0; i < 2; ++i) {
                int c = tid + i * 256;
                int r = c >> 3, pc = c & 7, lc = pc ^ (r & 7);
                kreg[i] = *(const uint4*)(qkv + (long long)(b * T_ + ktn * 64 + r) * 1536
                                          + 512 + h * 64 + lc * 8);
                vreg[i] = *(const uint4*)(vt + ((long long)bh * 64 + r) * T_
                                          + ktn * 64 + lc * 8);
            }
            if (tid < 64) mreg = mask[b * T_ + ktn * 64 + tid];
        }

        const float mkv = maskK[cbuf][lane];
        const bool tile_clean = (__ballot(mkv == 0.f) == 0ull);
        const bool fast = tile_clean && (mi != 0.f);
        const bool has_band = (kt * 64 <= q0 + w * 16 + 19) &&
                              (kt * 64 + 67 >= q0 + w * 16);

        f32x4 sacc[4];
#pragma unroll
        for (int ni = 0; ni < 4; ++ni) sacc[ni] = vzero;
        __builtin_amdgcn_s_setprio(1);
#pragma unroll
        for (int ks = 0; ks < 2; ++ks)
#pragma unroll
            for (int ni = 0; ni < 4; ++ni) {
                int r = ni * 16 + l16;
                int pc = ((ks << 2) | quad) ^ (r & 7);
                bf16x8 kf = *(const bf16x8*)&Kt[cbuf][r * 64 + pc * 8];
                sacc[ni] = __builtin_amdgcn_mfma_f32_16x16x32_bf16(kf, qf[ks], sacc[ni], 0, 0, 0);
            }
        __builtin_amdgcn_s_setprio(0);

        if (has_band) {
#pragma unroll
            for (int ni = 0; ni < 4; ++ni)
#pragma unroll
                for (int r = 0; r < 4; ++r) {
                    int jl = ni * 16 + quad * 4 + r;
                    int dlt = kt * 64 + jl - i_row;
                    if (dlt >= -4 && dlt <= 4)
                        sacc[ni][r] += bandk[w * 16 + l16][dlt + 4];
                }
        }
        if (!fast) {
#pragma unroll
            for (int ni = 0; ni < 4; ++ni)
#pragma unroll
                for (int r = 0; r < 4; ++r) {
                    int jl = ni * 16 + quad * 4 + r;
                    if (mi * maskK[cbuf][jl] == 0.f) sacc[ni][r] = -10000.0f;
                }
        }

        float mx = -1e30f;
#pragma unroll
        for (int ni = 0; ni < 4; ++ni)
#pragma unroll
            for (int r = 0; r < 4; ++r) mx = fmaxf(mx, sacc[ni][r]);
        mx = fmaxf(mx, __shfl_xor(mx, 16));
        mx = fmaxf(mx, __shfl_xor(mx, 32));
        float m_new = fmaxf(m_run, mx);
        float alpha = __expf(m_run - m_new);
        m_run = m_new;
        l_run *= alpha;
#pragma unroll
        for (int ni = 0; ni < 4; ++ni) vacc[ni] = vacc[ni] * alpha;
#pragma unroll
        for (int k = 0; k < 3; ++k) pb[k] *= alpha;

        float lsum = 0.f;
#pragma unroll
        for (int ni = 0; ni < 4; ++ni) {
            u16 pk[4];
#pragma unroll
            for (int r = 0; r < 4; ++r) {
                float u = __expf(sacc[ni][r] - m_new);
                lsum += u;
                pk[r] = f2b(u);
            }
            int c0 = ni * 16 + quad * 4;
            int phys = (((c0 >> 3) ^ (l16 & 7)) << 3) + (c0 & 7);
            uint2 p;
            p.x = (uint32_t)pk[0] | ((uint32_t)pk[1] << 16);
            p.y = (uint32_t)pk[2] | ((uint32_t)pk[3] << 16);
            *(uint2*)&Pl[w][l16 * 64 + phys] = p;
        }
        l_run += lsum;

        if (has_band) {
#pragma unroll
            for (int k = 0; k < 3; ++k) {
                int e = quad * 3 + k;
                if (e < 9) {
                    int jl = i_row + e - 4 - kt * 64;
                    if (jl >= 0 && jl < 64) {
                        int phys = (((jl >> 3) ^ (l16 & 7)) << 3) + (jl & 7);
                        pb[k] += b2f(Pl[w][l16 * 64 + phys]);
                    }
                }
            }
        }

        __builtin_amdgcn_s_setprio(1);
#pragma unroll
        for (int ks = 0; ks < 2; ++ks) {
            int pcc = ((ks << 2) | quad) ^ (l16 & 7);
            bf16x8 pf = *(const bf16x8*)&Pl[w][l16 * 64 + pcc * 8];
#pragma unroll
            for (int ni = 0; ni < 4; ++ni) {
                int r = ni * 16 + l16;
                int pc = ((ks << 2) | quad) ^ (r & 7);
                bf16x8 vf = *(const bf16x8*)&Vt[cbuf][r * 64 + pc * 8];
                vacc[ni] = __builtin_amdgcn_mfma_f32_16x16x32_bf16(vf, pf, vacc[ni], 0, 0, 0);
            }
        }
        __builtin_amdgcn_s_setprio(0);

        if (pre) {
#pragma unroll
            for (int i = 0; i < 2; ++i) {
                int c = tid + i * 256;
                *(uint4*)&Kt[cbuf ^ 1][c * 8] = kreg[i];
                *(uint4*)&Vt[cbuf ^ 1][c * 8] = vreg[i];
            }
            if (tid < 64) maskK[cbuf ^ 1][tid] = mreg;
            __syncthreads();
            cbuf ^= 1;
        }
    }

    l_run += __shfl_xor(l_run, 16);
    l_run += __shfl_xor(l_run, 32);
    const float rinv = 1.f / l_run;

    float pband[9];
#pragma unroll
    for (int e = 0; e < 9; ++e) {
        float val = (quad == e / 3) ? pb[e % 3] : 0.f;
        val += __shfl_xor(val, 16);
        val += __shfl_xor(val, 32);
        pband[e] = val * rinv;
    }

    u16* orow = outb + (long long)(b * T_ + i_row) * C_ + h * 64;
#pragma unroll
    for (int ni = 0; ni < 4; ++ni) {
        u16 pk[4];
#pragma unroll
        for (int r = 0; r < 4; ++r) {
            int d = ni * 16 + quad * 4 + r;
            float v = vacc[ni][r] * rinv;
#pragma unroll
            for (int e = 0; e < 9; ++e) v += pband[e] * erv[e * 64 + d];
            pk[r] = f2b(v);
        }
        uint2 p;
        p.x = (uint32_t)pk[0] | ((uint32_t)pk[1] << 16);
        p.y = (uint32_t)pk[2] | ((uint32_t)pk[3] << 16);
        *(uint2*)(orow + ni * 16 + quad * 4) = p;
    }
}

// ---------------------------------------------------------------------------
// One-time weight transposes (f32 -> bf16), batched over layers.
// ---------------------------------------------------------------------------
__global__ void transpose_qkvo(const float* __restrict__ Wq, const float* __restrict__ Wk,
                               const float* __restrict__ Wv, const float* __restrict__ Wo,
                               u16* __restrict__ wqkvT, u16* __restrict__ woT)
{
    __shared__ u16 tile[32][33];
    const int z = blockIdx.z, l = z >> 2, which = z & 3;
    const float* src = (which == 0 ? Wq : which == 1 ? Wk : which == 2 ? Wv : Wo)
                       + (long long)l * 262144;
    u16* dst = (which == 3) ? woT + (long long)l * 262144
                            : wqkvT + (long long)l * 786432 + which * 262144;
    const int r0 = blockIdx.y * 32, c0 = blockIdx.x * 32;
    const int tx = threadIdx.x, ty = threadIdx.y;
#pragma unroll
    for (int i = 0; i < 32; i += 8)
        tile[ty + i][tx] = f2b(src[(long long)(r0 + ty + i) * 512 + (c0 + tx)]);
    __syncthreads();
#pragma unroll
    for (int i = 0; i < 32; i += 8)
        dst[(long long)(c0 + ty + i) * 512 + (r0 + tx)] = tile[tx][ty + i];
}

__global__ void transpose_f2bL(const float* __restrict__ src0, int sStride, long long sLayer,
                               u16* __restrict__ dst0, int dStride, long long dLayer)
{
    __shared__ u16 tile[32][33];
    const int l = blockIdx.z;
    const float* src = src0 + (long long)l * sLayer;
    u16* dst = dst0 + (long long)l * dLayer;
    const int r0 = blockIdx.y * 32, c0 = blockIdx.x * 32;
    const int tx = threadIdx.x, ty = threadIdx.y;
#pragma unroll
    for (int i = 0; i < 32; i += 8)
        tile[ty + i][tx] = f2b(src[(long long)(r0 + ty + i) * sStride + (c0 + tx)]);
    __syncthreads();
#pragma unroll
    for (int i = 0; i < 32; i += 8)
        dst[(long long)(c0 + ty + i) * dStride + (r0 + tx)] = tile[tx][ty + i];
}

__global__ void transpose_b(const u16* __restrict__ src, long long sB1, long long sB2, int sStride,
                            u16* __restrict__ dst, long long dB1, long long dB2, int dStride)
{
    __shared__ u16 tile[32][33];
    const int z = blockIdx.z, zb = z >> 3, zh = z & 7;
    src += (long long)zb * sB1 + (long long)zh * sB2;
    dst += (long long)zb * dB1 + (long long)zh * dB2;
    const int r0 = blockIdx.y * 32, c0 = blockIdx.x * 32;
    const int tx = threadIdx.x, ty = threadIdx.y;
#pragma unroll
    for (int i = 0; i < 32; i += 8)
        tile[ty + i][tx] = src[(long long)(r0 + ty + i) * sStride + (c0 + tx)];
    __syncthreads();
#pragma unroll
    for (int i = 0; i < 32; i += 8)
        dst[(long long)(c0 + ty + i) * dStride + (r0 + tx)] = tile[tx][ty + i];
}

__global__ void concat_bias(const float* __restrict__ bq, const float* __restrict__ bk,
                            const float* __restrict__ bv, float* __restrict__ dst)
{
    int i = blockIdx.x * 256 + threadIdx.x;
    int l = i / 1536, n = i - l * 1536;
    float v = (n < 512) ? bq[l * 512 + n]
             : (n < 1024 ? bk[l * 512 + (n - 512)] : bv[l * 512 + (n - 1024)]);
    dst[i] = v;
}

__global__ void mask_in(const float* __restrict__ x, const float* __restrict__ mask,
                        u16* __restrict__ out)
{
    int i4 = (blockIdx.x * 256 + threadIdx.x) * 4;
    float4 xv = *(const float4*)(x + i4);
    float m = mask[i4 >> 9];
    u16 pk[4] = {f2b(xv.x * m), f2b(xv.y * m), f2b(xv.z * m), f2b(xv.w * m)};
    uint2 p; p.x = (uint32_t)pk[0] | ((uint32_t)pk[1] << 16);
    p.y = (uint32_t)pk[2] | ((uint32_t)pk[3] << 16);
    *(uint2*)(out + i4) = p;
}

__global__ void mask_out(const u16* __restrict__ x, const float* __restrict__ mask,
                         float* __restrict__ out)
{
    int i4 = (blockIdx.x * 256 + threadIdx.x) * 4;
    uint2 p = *(const uint2*)(x + i4);
    float m = mask[i4 >> 9];
    float4 o;
    o.x = b2f((u16)(p.x & 0xffff)) * m;
    o.y = b2f((u16)(p.x >> 16)) * m;
    o.z = b2f((u16)(p.y & 0xffff)) * m;
    o.w = b2f((u16)(p.y >> 16)) * m;
    *(float4*)(out + i4) = o;
}

__global__ __launch_bounds__(256) void add_ln(
    const u16* __restrict__ x, const u16* __restrict__ y,
    const float* __restrict__ sc, const float* __restrict__ bi,
    u16* __restrict__ outx)
{
    const int wave = threadIdx.x >> 6, lane = threadIdx.x & 63;
    const long long r = (long long)blockIdx.x * 4 + wave;
    const u16* xr = x + r * C_;
    const u16* yr = y + r * C_;
    float v[8], s = 0.f;
#pragma unroll
    for (int it = 0; it < 2; ++it) {
        int j0 = it * 256 + lane * 4;
        uint2 px = *(const uint2*)(xr + j0);
        uint2 py = *(const uint2*)(yr + j0);
        v[it * 4 + 0] = b2f((u16)(px.x & 0xffff)) + b2f((u16)(py.x & 0xffff));
        v[it * 4 + 1] = b2f((u16)(px.x >> 16))    + b2f((u16)(py.x >> 16));
        v[it * 4 + 2] = b2f((u16)(px.y & 0xffff)) + b2f((u16)(py.y & 0xffff));
        v[it * 4 + 3] = b2f((u16)(px.y >> 16))    + b2f((u16)(py.y >> 16));
        s += v[it * 4 + 0] + v[it * 4 + 1] + v[it * 4 + 2] + v[it * 4 + 3];
    }
#pragma unroll
    for (int off = 32; off > 0; off >>= 1) s += __shfl_down(s, off);
    s = __shfl(s, 0);
    const float mean = s * (1.f / 512.f);
    float var = 0.f;
#pragma unroll
    for (int l = 0; l < 8; ++l) { float d = v[l] - mean; var += d * d; }
#pragma unroll
    for (int off = 32; off > 0; off >>= 1) var += __shfl_down(var, off);
    var = __shfl(var, 0);
    const float rs = rsqrtf(var * (1.f / 512.f) + 1e-6f);
    u16* orow = outx + r * C_;
#pragma unroll
    for (int it = 0; it < 2; ++it) {
        int j0 = it * 256 + lane * 4;
        float4 s4 = *(const float4*)(sc + j0);
        float4 b4 = *(const float4*)(bi + j0);
        u16 pk[4];
        pk[0] = f2b((v[it * 4 + 0] - mean) * rs * s4.x + b4.x);
        pk[1] = f2b((v[it * 4 + 1] - mean) * rs * s4.y + b4.y);
        pk[2] = f2b((v[it * 4 + 2] - mean) * rs * s4.z + b4.z);
        pk[3] = f2b((v[it * 4 + 3] - mean) * rs * s4.w + b4.w);
        uint2 p; p.x = (uint32_t)pk[0] | ((uint32_t)pk[1] << 16);
        p.y = (uint32_t)pk[2] | ((uint32_t)pk[3] << 16);
        *(uint2*)(orow + j0) = p;
    }
}

// ===========================================================================
extern "C" void kernel_launch(void* const* d_in, const int* in_sizes, int n_in,
                              void* d_out, int out_size, void* d_ws, size_t ws_size,
                              hipStream_t stream)
{
    const float* x    = (const float*)d_in[0];
    const float* mask = (const float*)d_in[1];
    const float* Wq   = (const float*)d_in[2];
    const float* bq   = (const float*)d_in[3];
    const float* Wk   = (const float*)d_in[4];
    const float* bk   = (const float*)d_in[5];
    const float* Wv   = (const float*)d_in[6];
    const float* bv   = (const float*)d_in[7];
    const float* Wo   = (const float*)d_in[8];
    const float* bo   = (const float*)d_in[9];
    const float* erk  = (const float*)d_in[10];
    const float* erv  = (const float*)d_in[11];
    const float* ln1s = (const float*)d_in[12];
    const float* ln1b = (const float*)d_in[13];
    const float* W1   = (const float*)d_in[14];
    const float* b1   = (const float*)d_in[15];
    const float* W2   = (const float*)d_in[16];
    const float* b2   = (const float*)d_in[17];
    const float* ln2s = (const float*)d_in[18];
    const float* ln2b = (const float*)d_in[19];
    float* out = (float*)d_out;
    u16* ws  = (u16*)d_ws;

    const long long CF = 512LL * 2048;
    const int M = B_ * T_;  // 6144

    // ws layout (u16 units). Total 51,234,816 u16 = 102.5 MB (<121.7 MB proven).
    u16* wqkvT   = ws;                      // [6][1536][512]
    u16* woT     = ws + 4718592;            // [6][512][512]
    u16* w1T     = ws + 6291456;            // [6][2048][512]
    u16* w2T     = ws + 12582912;           // [6][512][2048]
    float* bqkv  = (float*)(ws + 18874368); // [6][1536] f32
    u16* xb      = ws + 18892800;           // [M][512]
    u16* qkvb    = ws + 22038528;           // [M][1536]
    u16* vtb     = ws + 31475712;           // [64][64][768]; aliased as yb
    u16* attnb   = ws + 34621440;           // [M][512]
    u16* scr     = ws + 37767168;           // h1 [M][2048]
    float* bandg = (float*)(ws + 50350080); // [M][8][9] f32
    u16* yb      = vtb;

    const dim3 tb(32, 8);

    // --- one-time prologue ---
    transpose_qkvo<<<dim3(16, 16, 24), tb, 0, stream>>>(Wq, Wk, Wv, Wo, wqkvT, woT);
    transpose_f2bL<<<dim3(64, 16, 6), tb, 0, stream>>>(W1, 2048, CF, w1T, 512, 1048576);
    transpose_f2bL<<<dim3(16, 64, 6), tb, 0, stream>>>(W2, 512,  CF, w2T, 2048, 1048576);
    concat_bias<<<36, 256, 0, stream>>>(bq, bk, bv, bqkv);
    mask_in<<<(M * 512) / 1024, 256, 0, stream>>>(x, mask, xb);

    for (int l = 0; l < 6; ++l) {
        // QKV: [6144,512] @ [1536,512]^T; q *= 1/8 in epilogue
        gemm_bt<128, 3><<<dim3(48, 12, 1), 256, 0, stream>>>(
            xb, 0, 0, 512, wqkvT + (long long)l * 786432, 0, 0, 512, bqkv + l * 1536,
            qkvb, 0, 0, 1536, 512, 0.125f);
        // bandk table for this layer
        bandg_k<<<192, 256, 0, stream>>>(qkvb, erk + l * 576, bandg);
        // V^T per head: [64][768]
        transpose_b<<<dim3(2, 24, 64), tb, 0, stream>>>(
            qkvb + 1024, 768LL * 1536, 64, 1536,
            vtb, 8LL * 64 * 768, 64LL * 768, 768);
        // fused attention -> attnb
        flash_attn<<<dim3(12, 64), 256, 0, stream>>>(
            qkvb, vtb, mask, bandg, erv + l * 576, attnb);
        // O projection -> yb (=vtb, dead now): small-tile high-occupancy GEMM
        gemm_bt4<0><<<dim3(96, 8), 256, 0, stream>>>(
            attnb, 512, woT + (long long)l * 262144, 512, bo + l * 512,
            yb, 512, 512);
        add_ln<<<1536, 256, 0, stream>>>(xb, yb, ln1s + l * 512, ln1b + l * 512, xb);
        // FFN
        gemm_bt<128, 1><<<dim3(48, 16, 1), 256, 0, stream>>>(
            xb, 0, 0, 512, w1T + (long long)l * 1048576, 0, 0, 512, b1 + l * 2048,
            scr, 0, 0, 2048, 512, 0.f);
        gemm_bt4<0><<<dim3(96, 8), 256, 0, stream>>>(
            scr, 2048, w2T + (long long)l * 1048576, 2048, b2 + l * 512,
            yb, 512, 2048);
        add_ln<<<1536, 256, 0, stream>>>(xb, yb, ln2s + l * 512, ln2b + l * 512, xb);
    }

    mask_out<<<(M * 512) / 1024, 256, 0, stream>>>(xb, mask, out);
}

// Round 5
// 998.118 us; speedup vs baseline: 1.5712x; 1.0109x over previous
//
#include <hip/hip_runtime.h>
#include <stdint.h>

// ============================================================================
// Encoder (6-layer rel-pos transformer), MI355X. f32 in/out, bf16 internals.
// R10: R9's A/B proved the 64x64/4-wave gemm_bt4 beats the big-tile 2-barrier
// gemm_bt at these shapes (FFN2: 42 -> ~26 us, same FLOPs). Apply bt4 to QKV
// (grid 96x24, EPI=3 q-scale) and FFN1 (96x32, EPI=1 relu) as well; all four
// GEMMs now run the proven high-occupancy geometry. flash_attn unchanged.
// ============================================================================

typedef unsigned short u16;
typedef __attribute__((ext_vector_type(8))) __bf16 bf16x8;
typedef __attribute__((ext_vector_type(4))) float f32x4;

#define B_ 8
#define T_ 768
#define C_ 512
#define F_ 2048

__device__ __forceinline__ float b2f(u16 u) {
    union { float f; uint32_t i; } x; x.i = ((uint32_t)u) << 16; return x.f;
}
__device__ __forceinline__ u16 f2b(float f) {
    union { float f; uint32_t i; } x; x.f = f;
    return (u16)((x.i + 0x7fffu + ((x.i >> 16) & 1u)) >> 16);  // RNE
}

// ---------------------------------------------------------------------------
// gemm_bt4: 64x64 block, 256 threads, 4 waves (2x2), each wave 32x32 output.
// Same-iteration uint4 global->LDS staging (proven no-spill), two barriers
// per K-step, setprio around MFMA. EPI: 0=bias, 1=bias+relu, 3=bias+q-scale
// (cols<512 scaled by epiScale — QKV fused q/8).
// ---------------------------------------------------------------------------
template <int EPI>
__global__ __launch_bounds__(256) void gemm_bt4(
    const u16* __restrict__ A, int aStride,
    const u16* __restrict__ Bt, int bStride,
    const float* __restrict__ bias,
    u16* __restrict__ out, int oStride, int K, float epiScale)
{
    const int tid = threadIdx.x;
    const int wave = tid >> 6, lane = tid & 63;
    const int wm = wave & 1, wn = wave >> 1;
    const int quad = lane >> 4, l16 = lane & 15;
    const int m0 = blockIdx.x * 64;
    const int n0 = blockIdx.y * 64;

    __shared__ u16 As[64 * 64];
    __shared__ u16 Bs[64 * 64];

    const f32x4 vzero = {0.f, 0.f, 0.f, 0.f};
    f32x4 acc[2][2];
#pragma unroll
    for (int i = 0; i < 2; ++i)
#pragma unroll
        for (int j = 0; j < 2; ++j) acc[i][j] = vzero;

    for (int k0 = 0; k0 < K; k0 += 64) {
#pragma unroll
        for (int i = 0; i < 2; ++i) {
            int c = tid + i * 256;
            int row = c >> 3, pc = c & 7, lc = pc ^ (row & 7);
            *(uint4*)&As[c * 8] =
                *(const uint4*)(A + (long long)(m0 + row) * aStride + (k0 + lc * 8));
            *(uint4*)&Bs[c * 8] =
                *(const uint4*)(Bt + (long long)(n0 + row) * bStride + (k0 + lc * 8));
        }
        __syncthreads();
        __builtin_amdgcn_s_setprio(1);
#pragma unroll
        for (int ks = 0; ks < 2; ++ks) {
            bf16x8 af[2], bfr[2];
#pragma unroll
            for (int mi = 0; mi < 2; ++mi) {
                int row = wm * 32 + mi * 16 + l16;
                int pc = ((ks << 2) | quad) ^ (row & 7);
                af[mi] = *(const bf16x8*)&As[row * 64 + pc * 8];
            }
#pragma unroll
            for (int ni = 0; ni < 2; ++ni) {
                int row = wn * 32 + ni * 16 + l16;
                int pc = ((ks << 2) | quad) ^ (row & 7);
                bfr[ni] = *(const bf16x8*)&Bs[row * 64 + pc * 8];
            }
#pragma unroll
            for (int mi = 0; mi < 2; ++mi)
#pragma unroll
                for (int ni = 0; ni < 2; ++ni)
                    acc[mi][ni] = __builtin_amdgcn_mfma_f32_16x16x32_bf16(
                        bfr[ni], af[mi], acc[mi][ni], 0, 0, 0);
        }
        __builtin_amdgcn_s_setprio(0);
        __syncthreads();
    }

#pragma unroll
    for (int mi = 0; mi < 2; ++mi) {
        int row = m0 + wm * 32 + mi * 16 + l16;
#pragma unroll
        for (int ni = 0; ni < 2; ++ni) {
            int colb = n0 + wn * 32 + ni * 16 + quad * 4;
            u16 pk[4];
#pragma unroll
            for (int r = 0; r < 4; ++r) {
                float v = acc[mi][ni][r] + bias[colb + r];
                if (EPI == 1) v = v > 0.f ? v : 0.f;
                if (EPI == 3) { if (colb + r < 512) v *= epiScale; }
                pk[r] = f2b(v);
            }
            uint2 p;
            p.x = (uint32_t)pk[0] | ((uint32_t)pk[1] << 16);
            p.y = (uint32_t)pk[2] | ((uint32_t)pk[3] << 16);
            *(uint2*)(out + (long long)row * oStride + colb) = p;
        }
    }
}

// ---------------------------------------------------------------------------
// bandg[(t*8 + h)*9 + e] = q~[t,h,:] . erk[e,:]   (q pre-scaled by 1/8)
// ---------------------------------------------------------------------------
__global__ __launch_bounds__(256) void bandg_k(
    const u16* __restrict__ qkv, const float* __restrict__ erk,
    float* __restrict__ bandg)
{
    __shared__ float erkS[576];
    const int tid = threadIdx.x;
    for (int idx = tid; idx < 576; idx += 256) erkS[idx] = erk[idx];
    __syncthreads();
    const int gid = blockIdx.x * 256 + tid;       // 49152
    const int row = gid >> 3, h = gid & 7;
    const u16* q = qkv + (long long)row * 1536 + h * 64;
    float acc[9];
#pragma unroll
    for (int e = 0; e < 9; ++e) acc[e] = 0.f;
#pragma unroll
    for (int c = 0; c < 8; ++c) {
        uint4 d4 = *(const uint4*)(q + c * 8);
        const uint32_t dw[4] = {d4.x, d4.y, d4.z, d4.w};
#pragma unroll
        for (int j = 0; j < 8; ++j) {
            u16 uu = (u16)((dw[j >> 1] >> ((j & 1) * 16)) & 0xffff);
            float qv = b2f(uu);
            int d = c * 8 + j;
#pragma unroll
            for (int e = 0; e < 9; ++e) acc[e] += qv * erkS[e * 64 + d];
        }
    }
    float* o = bandg + (long long)gid * 9;
#pragma unroll
    for (int e = 0; e < 9; ++e) o[e] = acc[e];
}

// ---------------------------------------------------------------------------
// Flash attention v2 + R6 pipeline (unchanged — verified).
// ---------------------------------------------------------------------------
__global__ __launch_bounds__(256) void flash_attn(
    const u16* __restrict__ qkv, const u16* __restrict__ vt,
    const float* __restrict__ mask, const float* __restrict__ bandg,
    const float* __restrict__ erv, u16* __restrict__ outb)
{
    const int tid = threadIdx.x;
    const int w = tid >> 6, lane = tid & 63;
    const int quad = lane >> 4, l16 = lane & 15;
    const int orig = blockIdx.y * 12 + blockIdx.x;
    const int swz = (orig & 7) * 96 + (orig >> 3);
    const int qt = swz % 12, bh = swz / 12;
    const int b = bh >> 3, h = bh & 7;
    const int q0 = qt * 64;

    __shared__ u16 Ql[64 * 64];
    __shared__ u16 Kt[2][64 * 64];
    __shared__ u16 Vt[2][64 * 64];
    __shared__ u16 Pl[4][16 * 64];
    __shared__ float bandk[64][10];
    __shared__ float maskK[2][64];

#pragma unroll
    for (int i = 0; i < 2; ++i) {
        int c = tid + i * 256;
        int r = c >> 3, pc = c & 7, lc = pc ^ (r & 7);
        *(uint4*)&Ql[c * 8] =
            *(const uint4*)(qkv + (long long)(b * T_ + q0 + r) * 1536 + h * 64 + lc * 8);
    }
#pragma unroll
    for (int i = 0; i < 2; ++i) {
        int c = tid + i * 256;
        int r = c >> 3, pc = c & 7, lc = pc ^ (r & 7);
        *(uint4*)&Kt[0][c * 8] =
            *(const uint4*)(qkv + (long long)(b * T_ + r) * 1536 + 512 + h * 64 + lc * 8);
        *(uint4*)&Vt[0][c * 8] =
            *(const uint4*)(vt + ((long long)bh * 64 + r) * T_ + lc * 8);
    }
    if (tid < 64) maskK[0][tid] = mask[b * T_ + tid];
    for (int idx = tid; idx < 576; idx += 256) {
        int r = idx / 9, e = idx - r * 9;
        bandk[r][e] = bandg[((long long)(b * T_ + q0 + r) * 8 + h) * 9 + e];
    }

    const int i_row = q0 + w * 16 + l16;
    const float mi = mask[b * T_ + i_row];
    float m_run = -1e30f, l_run = 0.f;
    const f32x4 vzero = {0.f, 0.f, 0.f, 0.f};
    f32x4 vacc[4] = {vzero, vzero, vzero, vzero};
    float pb[3] = {0.f, 0.f, 0.f};

    __syncthreads();
    bf16x8 qf[2];
#pragma unroll
    for (int ks = 0; ks < 2; ++ks) {
        int r = w * 16 + l16;
        int pc = ((ks << 2) | quad) ^ (r & 7);
        qf[ks] = *(const bf16x8*)&Ql[r * 64 + pc * 8];
    }

    int cbuf = 0;
    for (int kt = 0; kt < 12; ++kt) {
        uint4 kreg[2], vreg[2];
        float mreg = 0.f;
        const bool pre = (kt < 11);
        if (pre) {
            const int ktn = kt + 1;
#pragma unroll
            for (int i = 0; i < 2; ++i) {
                int c = tid + i * 256;
                int r = c >> 3, pc = c & 7, lc = pc ^ (r & 7);
                kreg[i] = *(const uint4*)(qkv + (long long)(b * T_ + ktn * 64 + r) * 1536
                                          + 512 + h * 64 + lc * 8);
                vreg[i] = *(const uint4*)(vt + ((long long)bh * 64 + r) * T_
                                          + ktn * 64 + lc * 8);
            }
            if (tid < 64) mreg = mask[b * T_ + ktn * 64 + tid];
        }

        const float mkv = maskK[cbuf][lane];
        const bool tile_clean = (__ballot(mkv == 0.f) == 0ull);
        const bool fast = tile_clean && (mi != 0.f);
        const bool has_band = (kt * 64 <= q0 + w * 16 + 19) &&
                              (kt * 64 + 67 >= q0 + w * 16);

        f32x4 sacc[4];
#pragma unroll
        for (int ni = 0; ni < 4; ++ni) sacc[ni] = vzero;
        __builtin_amdgcn_s_setprio(1);
#pragma unroll
        for (int ks = 0; ks < 2; ++ks)
#pragma unroll
            for (int ni = 0; ni < 4; ++ni) {
                int r = ni * 16 + l16;
                int pc = ((ks << 2) | quad) ^ (r & 7);
                bf16x8 kf = *(const bf16x8*)&Kt[cbuf][r * 64 + pc * 8];
                sacc[ni] = __builtin_amdgcn_mfma_f32_16x16x32_bf16(kf, qf[ks], sacc[ni], 0, 0, 0);
            }
        __builtin_amdgcn_s_setprio(0);

        if (has_band) {
#pragma unroll
            for (int ni = 0; ni < 4; ++ni)
#pragma unroll
                for (int r = 0; r < 4; ++r) {
                    int jl = ni * 16 + quad * 4 + r;
                    int dlt = kt * 64 + jl - i_row;
                    if (dlt >= -4 && dlt <= 4)
                        sacc[ni][r] += bandk[w * 16 + l16][dlt + 4];
                }
        }
        if (!fast) {
#pragma unroll
            for (int ni = 0; ni < 4; ++ni)
#pragma unroll
                for (int r = 0; r < 4; ++r) {
                    int jl = ni * 16 + quad * 4 + r;
                    if (mi * maskK[cbuf][jl] == 0.f) sacc[ni][r] = -10000.0f;
                }
        }

        float mx = -1e30f;
#pragma unroll
        for (int ni = 0; ni < 4; ++ni)
#pragma unroll
            for (int r = 0; r < 4; ++r) mx = fmaxf(mx, sacc[ni][r]);
        mx = fmaxf(mx, __shfl_xor(mx, 16));
        mx = fmaxf(mx, __shfl_xor(mx, 32));
        float m_new = fmaxf(m_run, mx);
        float alpha = __expf(m_run - m_new);
        m_run = m_new;
        l_run *= alpha;
#pragma unroll
        for (int ni = 0; ni < 4; ++ni) vacc[ni] = vacc[ni] * alpha;
#pragma unroll
        for (int k = 0; k < 3; ++k) pb[k] *= alpha;

        float lsum = 0.f;
#pragma unroll
        for (int ni = 0; ni < 4; ++ni) {
            u16 pk[4];
#pragma unroll
            for (int r = 0; r < 4; ++r) {
                float u = __expf(sacc[ni][r] - m_new);
                lsum += u;
                pk[r] = f2b(u);
            }
            int c0 = ni * 16 + quad * 4;
            int phys = (((c0 >> 3) ^ (l16 & 7)) << 3) + (c0 & 7);
            uint2 p;
            p.x = (uint32_t)pk[0] | ((uint32_t)pk[1] << 16);
            p.y = (uint32_t)pk[2] | ((uint32_t)pk[3] << 16);
            *(uint2*)&Pl[w][l16 * 64 + phys] = p;
        }
        l_run += lsum;

        if (has_band) {
#pragma unroll
            for (int k = 0; k < 3; ++k) {
                int e = quad * 3 + k;
                if (e < 9) {
                    int jl = i_row + e - 4 - kt * 64;
                    if (jl >= 0 && jl < 64) {
                        int phys = (((jl >> 3) ^ (l16 & 7)) << 3) + (jl & 7);
                        pb[k] += b2f(Pl[w][l16 * 64 + phys]);
                    }
                }
            }
        }

        __builtin_amdgcn_s_setprio(1);
#pragma unroll
        for (int ks = 0; ks < 2; ++ks) {
            int pcc = ((ks << 2) | quad) ^ (l16 & 7);
            bf16x8 pf = *(const bf16x8*)&Pl[w][l16 * 64 + pcc * 8];
#pragma unroll
            for (int ni = 0; ni < 4; ++ni) {
                int r = ni * 16 + l16;
                int pc = ((ks << 2) | quad) ^ (r & 7);
                bf16x8 vf = *(const bf16x8*)&Vt[cbuf][r * 64 + pc * 8];
                vacc[ni] = __builtin_amdgcn_mfma_f32_16x16x32_bf16(vf, pf, vacc[ni], 0, 0, 0);
            }
        }
        __builtin_amdgcn_s_setprio(0);

        if (pre) {
#pragma unroll
            for (int i = 0; i < 2; ++i) {
                int c = tid + i * 256;
                *(uint4*)&Kt[cbuf ^ 1][c * 8] = kreg[i];
                *(uint4*)&Vt[cbuf ^ 1][c * 8] = vreg[i];
            }
            if (tid < 64) maskK[cbuf ^ 1][tid] = mreg;
            __syncthreads();
            cbuf ^= 1;
        }
    }

    l_run += __shfl_xor(l_run, 16);
    l_run += __shfl_xor(l_run, 32);
    const float rinv = 1.f / l_run;

    float pband[9];
#pragma unroll
    for (int e = 0; e < 9; ++e) {
        float val = (quad == e / 3) ? pb[e % 3] : 0.f;
        val += __shfl_xor(val, 16);
        val += __shfl_xor(val, 32);
        pband[e] = val * rinv;
    }

    u16* orow = outb + (long long)(b * T_ + i_row) * C_ + h * 64;
#pragma unroll
    for (int ni = 0; ni < 4; ++ni) {
        u16 pk[4];
#pragma unroll
        for (int r = 0; r < 4; ++r) {
            int d = ni * 16 + quad * 4 + r;
            float v = vacc[ni][r] * rinv;
#pragma unroll
            for (int e = 0; e < 9; ++e) v += pband[e] * erv[e * 64 + d];
            pk[r] = f2b(v);
        }
        uint2 p;
        p.x = (uint32_t)pk[0] | ((uint32_t)pk[1] << 16);
        p.y = (uint32_t)pk[2] | ((uint32_t)pk[3] << 16);
        *(uint2*)(orow + ni * 16 + quad * 4) = p;
    }
}

// ---------------------------------------------------------------------------
// One-time weight transposes (f32 -> bf16), batched over layers.
// ---------------------------------------------------------------------------
__global__ void transpose_qkvo(const float* __restrict__ Wq, const float* __restrict__ Wk,
                               const float* __restrict__ Wv, const float* __restrict__ Wo,
                               u16* __restrict__ wqkvT, u16* __restrict__ woT)
{
    __shared__ u16 tile[32][33];
    const int z = blockIdx.z, l = z >> 2, which = z & 3;
    const float* src = (which == 0 ? Wq : which == 1 ? Wk : which == 2 ? Wv : Wo)
                       + (long long)l * 262144;
    u16* dst = (which == 3) ? woT + (long long)l * 262144
                            : wqkvT + (long long)l * 786432 + which * 262144;
    const int r0 = blockIdx.y * 32, c0 = blockIdx.x * 32;
    const int tx = threadIdx.x, ty = threadIdx.y;
#pragma unroll
    for (int i = 0; i < 32; i += 8)
        tile[ty + i][tx] = f2b(src[(long long)(r0 + ty + i) * 512 + (c0 + tx)]);
    __syncthreads();
#pragma unroll
    for (int i = 0; i < 32; i += 8)
        dst[(long long)(c0 + ty + i) * 512 + (r0 + tx)] = tile[tx][ty + i];
}

__global__ void transpose_f2bL(const float* __restrict__ src0, int sStride, long long sLayer,
                               u16* __restrict__ dst0, int dStride, long long dLayer)
{
    __shared__ u16 tile[32][33];
    const int l = blockIdx.z;
    const float* src = src0 + (long long)l * sLayer;
    u16* dst = dst0 + (long long)l * dLayer;
    const int r0 = blockIdx.y * 32, c0 = blockIdx.x * 32;
    const int tx = threadIdx.x, ty = threadIdx.y;
#pragma unroll
    for (int i = 0; i < 32; i += 8)
        tile[ty + i][tx] = f2b(src[(long long)(r0 + ty + i) * sStride + (c0 + tx)]);
    __syncthreads();
#pragma unroll
    for (int i = 0; i < 32; i += 8)
        dst[(long long)(c0 + ty + i) * dStride + (r0 + tx)] = tile[tx][ty + i];
}

__global__ void transpose_b(const u16* __restrict__ src, long long sB1, long long sB2, int sStride,
                            u16* __restrict__ dst, long long dB1, long long dB2, int dStride)
{
    __shared__ u16 tile[32][33];
    const int z = blockIdx.z, zb = z >> 3, zh = z & 7;
    src += (long long)zb * sB1 + (long long)zh * sB2;
    dst += (long long)zb * dB1 + (long long)zh * dB2;
    const int r0 = blockIdx.y * 32, c0 = blockIdx.x * 32;
    const int tx = threadIdx.x, ty = threadIdx.y;
#pragma unroll
    for (int i = 0; i < 32; i += 8)
        tile[ty + i][tx] = src[(long long)(r0 + ty + i) * sStride + (c0 + tx)];
    __syncthreads();
#pragma unroll
    for (int i = 0; i < 32; i += 8)
        dst[(long long)(c0 + ty + i) * dStride + (r0 + tx)] = tile[tx][ty + i];
}

__global__ void concat_bias(const float* __restrict__ bq, const float* __restrict__ bk,
                            const float* __restrict__ bv, float* __restrict__ dst)
{
    int i = blockIdx.x * 256 + threadIdx.x;
    int l = i / 1536, n = i - l * 1536;
    float v = (n < 512) ? bq[l * 512 + n]
             : (n < 1024 ? bk[l * 512 + (n - 512)] : bv[l * 512 + (n - 1024)]);
    dst[i] = v;
}

__global__ void mask_in(const float* __restrict__ x, const float* __restrict__ mask,
                        u16* __restrict__ out)
{
    int i4 = (blockIdx.x * 256 + threadIdx.x) * 4;
    float4 xv = *(const float4*)(x + i4);
    float m = mask[i4 >> 9];
    u16 pk[4] = {f2b(xv.x * m), f2b(xv.y * m), f2b(xv.z * m), f2b(xv.w * m)};
    uint2 p; p.x = (uint32_t)pk[0] | ((uint32_t)pk[1] << 16);
    p.y = (uint32_t)pk[2] | ((uint32_t)pk[3] << 16);
    *(uint2*)(out + i4) = p;
}

__global__ void mask_out(const u16* __restrict__ x, const float* __restrict__ mask,
                         float* __restrict__ out)
{
    int i4 = (blockIdx.x * 256 + threadIdx.x) * 4;
    uint2 p = *(const uint2*)(x + i4);
    float m = mask[i4 >> 9];
    float4 o;
    o.x = b2f((u16)(p.x & 0xffff)) * m;
    o.y = b2f((u16)(p.x >> 16)) * m;
    o.z = b2f((u16)(p.y & 0xffff)) * m;
    o.w = b2f((u16)(p.y >> 16)) * m;
    *(float4*)(out + i4) = o;
}

__global__ __launch_bounds__(256) void add_ln(
    const u16* __restrict__ x, const u16* __restrict__ y,
    const float* __restrict__ sc, const float* __restrict__ bi,
    u16* __restrict__ outx)
{
    const int wave = threadIdx.x >> 6, lane = threadIdx.x & 63;
    const long long r = (long long)blockIdx.x * 4 + wave;
    const u16* xr = x + r * C_;
    const u16* yr = y + r * C_;
    float v[8], s = 0.f;
#pragma unroll
    for (int it = 0; it < 2; ++it) {
        int j0 = it * 256 + lane * 4;
        uint2 px = *(const uint2*)(xr + j0);
        uint2 py = *(const uint2*)(yr + j0);
        v[it * 4 + 0] = b2f((u16)(px.x & 0xffff)) + b2f((u16)(py.x & 0xffff));
        v[it * 4 + 1] = b2f((u16)(px.x >> 16))    + b2f((u16)(py.x >> 16));
        v[it * 4 + 2] = b2f((u16)(px.y & 0xffff)) + b2f((u16)(py.y & 0xffff));
        v[it * 4 + 3] = b2f((u16)(px.y >> 16))    + b2f((u16)(py.y >> 16));
        s += v[it * 4 + 0] + v[it * 4 + 1] + v[it * 4 + 2] + v[it * 4 + 3];
    }
#pragma unroll
    for (int off = 32; off > 0; off >>= 1) s += __shfl_down(s, off);
    s = __shfl(s, 0);
    const float mean = s * (1.f / 512.f);
    float var = 0.f;
#pragma unroll
    for (int l = 0; l < 8; ++l) { float d = v[l] - mean; var += d * d; }
#pragma unroll
    for (int off = 32; off > 0; off >>= 1) var += __shfl_down(var, off);
    var = __shfl(var, 0);
    const float rs = rsqrtf(var * (1.f / 512.f) + 1e-6f);
    u16* orow = outx + r * C_;
#pragma unroll
    for (int it = 0; it < 2; ++it) {
        int j0 = it * 256 + lane * 4;
        float4 s4 = *(const float4*)(sc + j0);
        float4 b4 = *(const float4*)(bi + j0);
        u16 pk[4];
        pk[0] = f2b((v[it * 4 + 0] - mean) * rs * s4.x + b4.x);
        pk[1] = f2b((v[it * 4 + 1] - mean) * rs * s4.y + b4.y);
        pk[2] = f2b((v[it * 4 + 2] - mean) * rs * s4.z + b4.z);
        pk[3] = f2b((v[it * 4 + 3] - mean) * rs * s4.w + b4.w);
        uint2 p; p.x = (uint32_t)pk[0] | ((uint32_t)pk[1] << 16);
        p.y = (uint32_t)pk[2] | ((uint32_t)pk[3] << 16);
        *(uint2*)(orow + j0) = p;
    }
}

// ===========================================================================
extern "C" void kernel_launch(void* const* d_in, const int* in_sizes, int n_in,
                              void* d_out, int out_size, void* d_ws, size_t ws_size,
                              hipStream_t stream)
{
    const float* x    = (const float*)d_in[0];
    const float* mask = (const float*)d_in[1];
    const float* Wq   = (const float*)d_in[2];
    const float* bq   = (const float*)d_in[3];
    const float* Wk   = (const float*)d_in[4];
    const float* bk   = (const float*)d_in[5];
    const float* Wv   = (const float*)d_in[6];
    const float* bv   = (const float*)d_in[7];
    const float* Wo   = (const float*)d_in[8];
    const float* bo   = (const float*)d_in[9];
    const float* erk  = (const float*)d_in[10];
    const float* erv  = (const float*)d_in[11];
    const float* ln1s = (const float*)d_in[12];
    const float* ln1b = (const float*)d_in[13];
    const float* W1   = (const float*)d_in[14];
    const float* b1   = (const float*)d_in[15];
    const float* W2   = (const float*)d_in[16];
    const float* b2   = (const float*)d_in[17];
    const float* ln2s = (const float*)d_in[18];
    const float* ln2b = (const float*)d_in[19];
    float* out = (float*)d_out;
    u16* ws  = (u16*)d_ws;

    const long long CF = 512LL * 2048;
    const int M = B_ * T_;  // 6144

    // ws layout (u16 units). Total 51,234,816 u16 = 102.5 MB (<121.7 MB proven).
    u16* wqkvT   = ws;                      // [6][1536][512]
    u16* woT     = ws + 4718592;            // [6][512][512]
    u16* w1T     = ws + 6291456;            // [6][2048][512]
    u16* w2T     = ws + 12582912;           // [6][512][2048]
    float* bqkv  = (float*)(ws + 18874368); // [6][1536] f32
    u16* xb      = ws + 18892800;           // [M][512]
    u16* qkvb    = ws + 22038528;           // [M][1536]
    u16* vtb     = ws + 31475712;           // [64][64][768]; aliased as yb
    u16* attnb   = ws + 34621440;           // [M][512]
    u16* scr     = ws + 37767168;           // h1 [M][2048]
    float* bandg = (float*)(ws + 50350080); // [M][8][9] f32
    u16* yb      = vtb;

    const dim3 tb(32, 8);

    // --- one-time prologue ---
    transpose_qkvo<<<dim3(16, 16, 24), tb, 0, stream>>>(Wq, Wk, Wv, Wo, wqkvT, woT);
    transpose_f2bL<<<dim3(64, 16, 6), tb, 0, stream>>>(W1, 2048, CF, w1T, 512, 1048576);
    transpose_f2bL<<<dim3(16, 64, 6), tb, 0, stream>>>(W2, 512,  CF, w2T, 2048, 1048576);
    concat_bias<<<36, 256, 0, stream>>>(bq, bk, bv, bqkv);
    mask_in<<<(M * 512) / 1024, 256, 0, stream>>>(x, mask, xb);

    for (int l = 0; l < 6; ++l) {
        // QKV: [6144,512] @ [1536,512]^T; q *= 1/8 in epilogue (cols < 512)
        gemm_bt4<3><<<dim3(96, 24), 256, 0, stream>>>(
            xb, 512, wqkvT + (long long)l * 786432, 512, bqkv + l * 1536,
            qkvb, 1536, 512, 0.125f);
        // bandk table for this layer
        bandg_k<<<192, 256, 0, stream>>>(qkvb, erk + l * 576, bandg);
        // V^T per head: [64][768]
        transpose_b<<<dim3(2, 24, 64), tb, 0, stream>>>(
            qkvb + 1024, 768LL * 1536, 64, 1536,
            vtb, 8LL * 64 * 768, 64LL * 768, 768);
        // fused attention -> attnb
        flash_attn<<<dim3(12, 64), 256, 0, stream>>>(
            qkvb, vtb, mask, bandg, erv + l * 576, attnb);
        // O projection -> yb (=vtb, dead now)
        gemm_bt4<0><<<dim3(96, 8), 256, 0, stream>>>(
            attnb, 512, woT + (long long)l * 262144, 512, bo + l * 512,
            yb, 512, 512, 0.f);
        add_ln<<<1536, 256, 0, stream>>>(xb, yb, ln1s + l * 512, ln1b + l * 512, xb);
        // FFN1 (relu fused)
        gemm_bt4<1><<<dim3(96, 32), 256, 0, stream>>>(
            xb, 512, w1T + (long long)l * 1048576, 512, b1 + l * 2048,
            scr, 2048, 512, 0.f);
        // FFN2
        gemm_bt4<0><<<dim3(96, 8), 256, 0, stream>>>(
            scr, 2048, w2T + (long long)l * 1048576, 2048, b2 + l * 512,
            yb, 512, 2048, 0.f);
        add_ln<<<1536, 256, 0, stream>>>(xb, yb, ln2s + l * 512, ln2b + l * 512, xb);
    }

    mask_out<<<(M * 512) / 1024, 256, 0, stream>>>(xb, mask, out);
}